// Round 1
// baseline (285.046 us; speedup 1.0000x reference)
//
#include <hip/hip_runtime.h>
#include <hip/hip_bf16.h>

// Phase 1: per-node last event index via atomicMax.
__global__ void k_last_idx(const int* __restrict__ node_ids,
                           int* __restrict__ last_idx, int E) {
    int i = blockIdx.x * blockDim.x + threadIdx.x;
    if (i < E) {
        atomicMax(&last_idx[node_ids[i]], i);
    }
}

// Phase 2a: gather message rows. 32 threads per node, one float4 (16B) each.
// Row = 128 floats = 32 float4s = 512B contiguous -> coalesced within group.
__global__ void k_gather_msg(const float4* __restrict__ msg,
                             const int* __restrict__ last_idx,
                             float4* __restrict__ out_msg, int N) {
    int t = blockIdx.x * blockDim.x + threadIdx.x;
    int node = t >> 5;
    int q = t & 31;
    if (node >= N) return;
    int li = last_idx[node];
    float4 v = make_float4(0.f, 0.f, 0.f, 0.f);
    if (li >= 0) {
        v = msg[(size_t)li * 32 + q];
    }
    out_msg[(size_t)node * 32 + q] = v;
}

// Phase 2b: valid flag (0.0/1.0 float) + gathered times.
__global__ void k_valid_times(const float* __restrict__ times,
                              const int* __restrict__ last_idx,
                              float* __restrict__ out_valid,
                              float* __restrict__ out_times, int N) {
    int i = blockIdx.x * blockDim.x + threadIdx.x;
    if (i < N) {
        int li = last_idx[i];
        bool ok = (li >= 0);
        out_valid[i] = ok ? 1.0f : 0.0f;
        out_times[i] = ok ? times[li] : 0.0f;
    }
}

extern "C" void kernel_launch(void* const* d_in, const int* in_sizes, int n_in,
                              void* d_out, int out_size, void* d_ws, size_t ws_size,
                              hipStream_t stream) {
    const int*   node_ids = (const int*)d_in[0];
    const float* msg      = (const float*)d_in[1];
    const float* times    = (const float*)d_in[2];
    // d_in[3] is num_nodes on device; recover N from out_size instead:
    // out = valid[N] + msg[N*128] + times[N] => out_size = 130*N
    const int E = in_sizes[0];
    const int N = out_size / 130;

    float* out_valid = (float*)d_out;
    float* out_msg   = (float*)d_out + N;
    float* out_times = (float*)d_out + N + (size_t)N * 128;

    int* last_idx = (int*)d_ws;  // N ints (4 MB), ws_size is ample

    // last_idx[i] = -1 for all i (0xFFFFFFFF == -1 as int32)
    hipMemsetAsync(last_idx, 0xFF, (size_t)N * sizeof(int), stream);

    const int B = 256;
    k_last_idx<<<(E + B - 1) / B, B, 0, stream>>>(node_ids, last_idx, E);

    // 32 threads per node for the msg gather
    long long total = (long long)N * 32;
    k_gather_msg<<<(int)((total + B - 1) / B), B, 0, stream>>>(
        (const float4*)msg, last_idx, (float4*)out_msg, N);

    k_valid_times<<<(N + B - 1) / B, B, 0, stream>>>(
        times, last_idx, out_valid, out_times, N);
}